// Round 1
// baseline (1362.502 us; speedup 1.0000x reference)
//
#include <hip/hip_runtime.h>
#include <math.h>

// Problem constants (B,L,H,P) = (4,4096,512,512)
#define Bz 4
#define Lz 4096
#define Hz 512
#define Pz 512
#define Nz (Bz*Lz)          // 16384 rows
#define Kz 512              // all GEMM K dims
#define CL 64               // scan chunk length
#define NC (Lz/CL)          // 64 chunks
#define EPSf 1e-5f

__device__ __forceinline__ float gelu_exact(float x){
    return 0.5f * x * (1.0f + erff(x * 0.70710678118654752f));
}

// ---------------- setup: per-state SSM params ----------------
__global__ void setup_kernel(const float* __restrict__ Lre, const float* __restrict__ Lim,
                             const float* __restrict__ log_step,
                             float* __restrict__ LamBarRe, float* __restrict__ LamBarIm,
                             float* __restrict__ fRe, float* __restrict__ fIm,
                             float* __restrict__ ApowRe, float* __restrict__ ApowIm){
    int p = blockIdx.x*blockDim.x + threadIdx.x;
    if (p >= Pz) return;
    float lr = Lre[p], li = Lim[p];
    float dt = expf(log_step[p]);
    float ar = lr*dt, ai = li*dt;
    float e = expf(ar);
    float Abr = e*cosf(ai), Abi = e*sinf(ai);   // Lambda_bar = exp(Lam*dt)
    LamBarRe[p]=Abr; LamBarIm[p]=Abi;
    // f = (Lambda_bar - 1) / Lambda
    float nr = Abr - 1.0f, ni = Abi;
    float d2 = lr*lr + li*li;
    fRe[p] = (nr*lr + ni*li)/d2;
    fIm[p] = (ni*lr - nr*li)/d2;
    // A^CL = exp(Lam*dt*CL)
    float arC = ar*(float)CL, aiC = ai*(float)CL;
    float eC = expf(arC);
    ApowRe[p] = eC*cosf(aiC);
    ApowIm[p] = eC*sinf(aiC);
}

// ---------------- LayerNorm (one block per row, H=512) ----------------
__global__ __launch_bounds__(256) void ln_kernel(const float* __restrict__ in,
                                                 const float* __restrict__ w,
                                                 const float* __restrict__ b,
                                                 float* __restrict__ out){
    int row = blockIdx.x;
    int tid = threadIdx.x;
    const float* r = in + (size_t)row*Hz;
    float v0 = r[tid], v1 = r[tid+256];
    float s = v0+v1, q = v0*v0+v1*v1;
    #pragma unroll
    for (int o=32;o;o>>=1){ s += __shfl_down(s,o); q += __shfl_down(q,o); }
    __shared__ float ss[4], sq[4];
    __shared__ float mu_s, rs_s;
    int wid = tid>>6, lane = tid&63;
    if (lane==0){ ss[wid]=s; sq[wid]=q; }
    __syncthreads();
    if (tid==0){
        float S=ss[0]+ss[1]+ss[2]+ss[3];
        float Q=sq[0]+sq[1]+sq[2]+sq[3];
        float mu = S/(float)Hz;
        float var = Q/(float)Hz - mu*mu;
        mu_s = mu; rs_s = rsqrtf(var + EPSf);
    }
    __syncthreads();
    float mu = mu_s, rs = rs_s;
    float* o = out + (size_t)row*Hz;
    o[tid]     = (v0-mu)*rs*w[tid]    +b[tid];
    o[tid+256] = (v1-mu)*rs*w[tid+256]+b[tid+256];
}

// ---------------- GEMM 1: Bu = f * (fx @ B^T)  (complex) ----------------
// A [N,K], B0/B1 [P,K] row-major; out0/out1 [N,P]
__global__ __launch_bounds__(256) void gemm_bu(const float* __restrict__ A,
                                               const float* __restrict__ B0,
                                               const float* __restrict__ B1,
                                               const float* __restrict__ fRe,
                                               const float* __restrict__ fIm,
                                               float* __restrict__ O0,
                                               float* __restrict__ O1){
    __shared__ float As[16][64];
    __shared__ float B0s[16][64];
    __shared__ float B1s[16][64];
    int n0 = blockIdx.x * 64;
    int m0 = blockIdx.y * 64;
    int tid = threadIdx.x;
    int tx = tid & 15, ty = tid >> 4;
    float acc0[4][4] = {{0}}; float acc1[4][4] = {{0}};
    for (int kt = 0; kt < Kz; kt += 16) {
        for (int e = tid; e < 64*16; e += 256) {
            int r = e >> 4, k = e & 15;
            As[k][r]  = A [(size_t)(n0 + r)*Kz + kt + k];
            B0s[k][r] = B0[(size_t)(m0 + r)*Kz + kt + k];
            B1s[k][r] = B1[(size_t)(m0 + r)*Kz + kt + k];
        }
        __syncthreads();
        #pragma unroll
        for (int k = 0; k < 16; ++k) {
            float a[4], b0[4], b1[4];
            #pragma unroll
            for (int i=0;i<4;++i) a[i]  = As[k][ty*4+i];
            #pragma unroll
            for (int j=0;j<4;++j){ b0[j] = B0s[k][tx*4+j]; b1[j] = B1s[k][tx*4+j]; }
            #pragma unroll
            for (int i=0;i<4;++i)
                #pragma unroll
                for (int j=0;j<4;++j){ acc0[i][j] += a[i]*b0[j]; acc1[i][j] += a[i]*b1[j]; }
        }
        __syncthreads();
    }
    #pragma unroll
    for (int i=0;i<4;++i)
        #pragma unroll
        for (int j=0;j<4;++j){
            int n = n0 + ty*4 + i, m = m0 + tx*4 + j;
            float gr = acc0[i][j], gi = acc1[i][j];
            float fr = fRe[m], fi = fIm[m];
            O0[(size_t)n*Pz + m] = fr*gr - fi*gi;
            O1[(size_t)n*Pz + m] = fr*gi + fi*gr;
        }
}

// ---------------- scan phase 1: per-chunk local end-state ----------------
__global__ __launch_bounds__(256) void scan_phase1(const float* __restrict__ BuRe,
                                                   const float* __restrict__ BuIm,
                                                   const float* __restrict__ ARe,
                                                   const float* __restrict__ AIm,
                                                   float* __restrict__ ERe,
                                                   float* __restrict__ EIm){
    int t = blockIdx.x;
    int pb = t & 1; t >>= 1;
    int c  = t % NC; t /= NC;
    int b  = t;
    int p  = pb*256 + threadIdx.x;
    size_t base = ((size_t)(b*Lz + c*CL))*Pz + p;
    float Ar = ARe[p], Ai = AIm[p];
    float xr = 0.f, xi = 0.f;
    for (int l = 0; l < CL; ++l) {
        float br = BuRe[base], bi = BuIm[base];
        float nr = Ar*xr - Ai*xi + br;
        float ni = Ar*xi + Ai*xr + bi;
        xr = nr; xi = ni;
        base += Pz;
    }
    size_t ci = ((size_t)(b*NC + c))*Pz + p;
    ERe[ci] = xr; EIm[ci] = xi;
}

// ---------------- scan combine: chunk carries (seq over 64 chunks) ----------------
__global__ __launch_bounds__(256) void scan_combine(const float* __restrict__ ERe,
                                                    const float* __restrict__ EIm,
                                                    const float* __restrict__ ApRe,
                                                    const float* __restrict__ ApIm,
                                                    float* __restrict__ SinRe,
                                                    float* __restrict__ SinIm){
    int gt = blockIdx.x*256 + threadIdx.x;   // over B*P
    int b = gt / Pz, p = gt % Pz;
    float Ar = ApRe[p], Ai = ApIm[p];
    float Sr = 0.f, Si = 0.f;
    for (int c = 0; c < NC; ++c) {
        size_t idx = ((size_t)(b*NC + c))*Pz + p;
        SinRe[idx] = Sr; SinIm[idx] = Si;
        float er = ERe[idx], ei = EIm[idx];
        float nr = Ar*Sr - Ai*Si + er;
        float ni = Ar*Si + Ai*Sr + ei;
        Sr = nr; Si = ni;
    }
}

// ---------------- scan phase 2: re-scan with carry-in, xs overwrites Bu ----------------
__global__ __launch_bounds__(256) void scan_phase2(float* __restrict__ BuRe,
                                                   float* __restrict__ BuIm,
                                                   const float* __restrict__ ARe,
                                                   const float* __restrict__ AIm,
                                                   const float* __restrict__ SinRe,
                                                   const float* __restrict__ SinIm){
    int t = blockIdx.x;
    int pb = t & 1; t >>= 1;
    int c  = t % NC; t /= NC;
    int b  = t;
    int p  = pb*256 + threadIdx.x;
    size_t base = ((size_t)(b*Lz + c*CL))*Pz + p;
    size_t ci = ((size_t)(b*NC + c))*Pz + p;
    float Ar = ARe[p], Ai = AIm[p];
    float xr = SinRe[ci], xi = SinIm[ci];
    for (int l = 0; l < CL; ++l) {
        float br = BuRe[base], bi = BuIm[base];
        float nr = Ar*xr - Ai*xi + br;
        float ni = Ar*xi + Ai*xr + bi;
        xr = nr; xi = ni;
        BuRe[base] = xr; BuIm[base] = xi;
        base += Pz;
    }
}

// ---------------- GEMM 2: y = 2*Re(xs @ C^T) + D*fx ; h = gelu(y)+fx ----------------
__global__ __launch_bounds__(256) void gemm_y(const float* __restrict__ A0,  // xsRe [N,P]
                                              const float* __restrict__ A1,  // xsIm
                                              const float* __restrict__ B0,  // C_re [H,P]
                                              const float* __restrict__ B1,  // C_im
                                              const float* __restrict__ Dv,
                                              const float* __restrict__ fx,
                                              float* __restrict__ Oh){
    __shared__ float A0s[16][64];
    __shared__ float A1s[16][64];
    __shared__ float B0s[16][64];
    __shared__ float B1s[16][64];
    int n0 = blockIdx.x * 64;
    int m0 = blockIdx.y * 64;
    int tid = threadIdx.x;
    int tx = tid & 15, ty = tid >> 4;
    float acc0[4][4] = {{0}}; float acc1[4][4] = {{0}};
    for (int kt = 0; kt < Kz; kt += 16) {
        for (int e = tid; e < 64*16; e += 256) {
            int r = e >> 4, k = e & 15;
            A0s[k][r] = A0[(size_t)(n0 + r)*Kz + kt + k];
            A1s[k][r] = A1[(size_t)(n0 + r)*Kz + kt + k];
            B0s[k][r] = B0[(size_t)(m0 + r)*Kz + kt + k];
            B1s[k][r] = B1[(size_t)(m0 + r)*Kz + kt + k];
        }
        __syncthreads();
        #pragma unroll
        for (int k = 0; k < 16; ++k) {
            float a0[4], a1[4], b0[4], b1[4];
            #pragma unroll
            for (int i=0;i<4;++i){ a0[i]=A0s[k][ty*4+i]; a1[i]=A1s[k][ty*4+i]; }
            #pragma unroll
            for (int j=0;j<4;++j){ b0[j]=B0s[k][tx*4+j]; b1[j]=B1s[k][tx*4+j]; }
            #pragma unroll
            for (int i=0;i<4;++i)
                #pragma unroll
                for (int j=0;j<4;++j){ acc0[i][j] += a0[i]*b0[j]; acc1[i][j] += a1[i]*b1[j]; }
        }
        __syncthreads();
    }
    #pragma unroll
    for (int i=0;i<4;++i)
        #pragma unroll
        for (int j=0;j<4;++j){
            int n = n0 + ty*4 + i, m = m0 + tx*4 + j;
            float fxv = fx[(size_t)n*Hz + m];
            float y = 2.0f*(acc0[i][j] - acc1[i][j]) + Dv[m]*fxv;
            Oh[(size_t)n*Hz + m] = gelu_exact(y) + fxv;
        }
}

// ---------------- GEMM 3: GEGLU — ff = (fx2@We_a^T) * gelu(fx2@We_g^T) ----------------
__global__ __launch_bounds__(256) void gemm_ff(const float* __restrict__ A,   // fx2 [N,H]
                                               const float* __restrict__ We,  // [2H,H]
                                               float* __restrict__ Off){
    __shared__ float As[16][64];
    __shared__ float B0s[16][64];
    __shared__ float B1s[16][64];
    int n0 = blockIdx.x * 64;
    int m0 = blockIdx.y * 64;
    int tid = threadIdx.x;
    int tx = tid & 15, ty = tid >> 4;
    float acc0[4][4] = {{0}}; float acc1[4][4] = {{0}};
    for (int kt = 0; kt < Kz; kt += 16) {
        for (int e = tid; e < 64*16; e += 256) {
            int r = e >> 4, k = e & 15;
            As[k][r]  = A [(size_t)(n0 + r)*Kz + kt + k];
            B0s[k][r] = We[(size_t)(m0 + r)*Kz + kt + k];            // a-rows
            B1s[k][r] = We[(size_t)(m0 + r + Hz)*Kz + kt + k];       // g-rows
        }
        __syncthreads();
        #pragma unroll
        for (int k = 0; k < 16; ++k) {
            float a[4], b0[4], b1[4];
            #pragma unroll
            for (int i=0;i<4;++i) a[i] = As[k][ty*4+i];
            #pragma unroll
            for (int j=0;j<4;++j){ b0[j]=B0s[k][tx*4+j]; b1[j]=B1s[k][tx*4+j]; }
            #pragma unroll
            for (int i=0;i<4;++i)
                #pragma unroll
                for (int j=0;j<4;++j){ acc0[i][j] += a[i]*b0[j]; acc1[i][j] += a[i]*b1[j]; }
        }
        __syncthreads();
    }
    #pragma unroll
    for (int i=0;i<4;++i)
        #pragma unroll
        for (int j=0;j<4;++j){
            int n = n0 + ty*4 + i, m = m0 + tx*4 + j;
            Off[(size_t)n*Hz + m] = acc0[i][j] * gelu_exact(acc1[i][j]);
        }
}

// ---------------- GEMM 4: out = ff @ Wd^T + fx2 ----------------
__global__ __launch_bounds__(256) void gemm_out(const float* __restrict__ A,   // ff [N,H]
                                                const float* __restrict__ Wd,  // [H,H]
                                                const float* __restrict__ fx2,
                                                float* __restrict__ O){
    __shared__ float As[16][64];
    __shared__ float Bs[16][64];
    int n0 = blockIdx.x * 64;
    int m0 = blockIdx.y * 64;
    int tid = threadIdx.x;
    int tx = tid & 15, ty = tid >> 4;
    float acc[4][4] = {{0}};
    for (int kt = 0; kt < Kz; kt += 16) {
        for (int e = tid; e < 64*16; e += 256) {
            int r = e >> 4, k = e & 15;
            As[k][r] = A [(size_t)(n0 + r)*Kz + kt + k];
            Bs[k][r] = Wd[(size_t)(m0 + r)*Kz + kt + k];
        }
        __syncthreads();
        #pragma unroll
        for (int k = 0; k < 16; ++k) {
            float a[4], b[4];
            #pragma unroll
            for (int i=0;i<4;++i) a[i] = As[k][ty*4+i];
            #pragma unroll
            for (int j=0;j<4;++j) b[j] = Bs[k][tx*4+j];
            #pragma unroll
            for (int i=0;i<4;++i)
                #pragma unroll
                for (int j=0;j<4;++j) acc[i][j] += a[i]*b[j];
        }
        __syncthreads();
    }
    #pragma unroll
    for (int i=0;i<4;++i)
        #pragma unroll
        for (int j=0;j<4;++j){
            int n = n0 + ty*4 + i, m = m0 + tx*4 + j;
            O[(size_t)n*Hz + m] = acc[i][j] + fx2[(size_t)n*Hz + m];
        }
}

extern "C" void kernel_launch(void* const* d_in, const int* in_sizes, int n_in,
                              void* d_out, int out_size, void* d_ws, size_t ws_size,
                              hipStream_t stream) {
    const float* x        = (const float*)d_in[0];
    const float* ln1_w    = (const float*)d_in[1];
    const float* ln1_b    = (const float*)d_in[2];
    const float* Lre      = (const float*)d_in[3];
    const float* Lim      = (const float*)d_in[4];
    const float* B_re     = (const float*)d_in[5];
    const float* B_im     = (const float*)d_in[6];
    const float* C_re     = (const float*)d_in[7];
    const float* C_im     = (const float*)d_in[8];
    const float* Dv       = (const float*)d_in[9];
    const float* log_step = (const float*)d_in[10];
    const float* ln2_w    = (const float*)d_in[11];
    const float* ln2_b    = (const float*)d_in[12];
    const float* W_enc    = (const float*)d_in[13];
    const float* W_dec    = (const float*)d_in[14];
    float* out = (float*)d_out;
    float* ws  = (float*)d_ws;

    size_t NH = (size_t)Nz*Hz;            // 8.39M
    size_t CS = (size_t)Bz*NC*Pz;         // 131072
    float* fx    = ws;                    // [N,H]  fx, later reused as ff
    float* BuRe  = ws + NH;               // [N,P]  Bu -> xs (in place)
    float* BuIm  = ws + 2*NH;
    float* hb    = ws + 3*NH;             // h, then fx2 (LN2 in place)
    float* ERe   = ws + 4*NH;
    float* EIm   = ERe + CS;
    float* SinRe = EIm + CS;
    float* SinIm = SinRe + CS;
    float* prm   = SinIm + CS;
    float* LamBarRe = prm;        float* LamBarIm = prm + Pz;
    float* fRe      = prm + 2*Pz; float* fIm      = prm + 3*Pz;
    float* ApRe     = prm + 4*Pz; float* ApIm     = prm + 5*Pz;

    setup_kernel<<<dim3(2), dim3(256), 0, stream>>>(Lre, Lim, log_step,
        LamBarRe, LamBarIm, fRe, fIm, ApRe, ApIm);

    ln_kernel<<<dim3(Nz), dim3(256), 0, stream>>>(x, ln1_w, ln1_b, fx);

    gemm_bu<<<dim3(Nz/64, Pz/64), dim3(256), 0, stream>>>(fx, B_re, B_im, fRe, fIm, BuRe, BuIm);

    scan_phase1<<<dim3(Bz*NC*(Pz/256)), dim3(256), 0, stream>>>(BuRe, BuIm, LamBarRe, LamBarIm, ERe, EIm);
    scan_combine<<<dim3((Bz*Pz)/256), dim3(256), 0, stream>>>(ERe, EIm, ApRe, ApIm, SinRe, SinIm);
    scan_phase2<<<dim3(Bz*NC*(Pz/256)), dim3(256), 0, stream>>>(BuRe, BuIm, LamBarRe, LamBarIm, SinRe, SinIm);

    gemm_y<<<dim3(Nz/64, Hz/64), dim3(256), 0, stream>>>(BuRe, BuIm, C_re, C_im, Dv, fx, hb);

    ln_kernel<<<dim3(Nz), dim3(256), 0, stream>>>(hb, ln2_w, ln2_b, hb);

    gemm_ff<<<dim3(Nz/64, Hz/64), dim3(256), 0, stream>>>(hb, W_enc, fx);   // fx buffer now holds ff

    gemm_out<<<dim3(Nz/64, Hz/64), dim3(256), 0, stream>>>(fx, W_dec, hb, out);
}

// Round 2
// 227.043 us; speedup vs baseline: 6.0011x; 6.0011x over previous
//
#include <hip/hip_runtime.h>
#include <math.h>

// (B,L,H,P) = (4,4096,512,512)
#define Bz 4
#define Lz 4096
#define Hz 512
#define Pz 512
#define Nz (Bz*Lz)          // 16384 rows
#define CL 64               // scan chunk length
#define NC (Lz/CL)          // 64 chunks
#define CS (Bz*NC*Pz)       // 131072 carry slots
#define EPSf 1e-5f

typedef unsigned short u16;
typedef unsigned int   u32;
typedef __attribute__((ext_vector_type(8))) short bf16x8;
typedef __attribute__((ext_vector_type(4))) float f32x4;

__device__ __forceinline__ float gelu_exact(float x){
    return 0.5f * x * (1.0f + erff(x * 0.70710678118654752f));
}
__device__ __forceinline__ u16 f2b(float f){
    union { float f; u32 u; } v; v.f = f;
    u32 u = v.u;
    u32 r = (u + 0x7FFFu + ((u >> 16) & 1u)) >> 16;   // RTNE
    return (u16)r;
}
__device__ __forceinline__ float b2f(u16 h){
    union { u32 u; float f; } v; v.u = ((u32)h) << 16; return v.f;
}

__device__ __forceinline__ void gload_lds16(const u16* g, u16* l){
    __builtin_amdgcn_global_load_lds(
        (const __attribute__((address_space(1))) void*)g,
        (__attribute__((address_space(3))) void*)l, 16, 0, 0);
}

// ---------------- setup: per-state SSM params ----------------
__global__ void setup_kernel(const float* __restrict__ Lre, const float* __restrict__ Lim,
                             const float* __restrict__ log_step,
                             float* __restrict__ prm){
    int p = blockIdx.x*blockDim.x + threadIdx.x;
    if (p >= Pz) return;
    float lr = Lre[p], li = Lim[p];
    float dt = expf(log_step[p]);
    float ar = lr*dt, ai = li*dt;
    float e = expf(ar);
    float Abr = e*cosf(ai), Abi = e*sinf(ai);   // Lambda_bar
    prm[p]        = Abr;   // LamBarRe
    prm[Pz + p]   = Abi;   // LamBarIm
    float nr = Abr - 1.0f, ni = Abi;
    float d2 = lr*lr + li*li;
    prm[2*Pz + p] = (nr*lr + ni*li)/d2;   // fRe
    prm[3*Pz + p] = (ni*lr - nr*li)/d2;   // fIm
    float arC = ar*(float)CL, aiC = ai*(float)CL;
    float eC = expf(arC);
    prm[4*Pz + p] = eC*cosf(aiC);         // ApowRe
    prm[5*Pz + p] = eC*sinf(aiC);         // ApowIm
}

// ---------------- weight converts ----------------
__global__ void cvt_f2b_kernel(const float* __restrict__ src, u16* __restrict__ dst, int n){
    int i = blockIdx.x*256 + threadIdx.x;
    if (i < n) dst[i] = f2b(src[i]);
}
__global__ void cvt_ccat_kernel(const float* __restrict__ Cre, const float* __restrict__ Cim,
                                u16* __restrict__ dst){
    int i = blockIdx.x*256 + threadIdx.x;   // over 512*512
    int h = i >> 9, p = i & 511;
    dst[(size_t)h*1024 + p]       = f2b(Cre[i]);
    dst[(size_t)h*1024 + 512 + p] = f2b(-Cim[i]);
}

// ---------------- LayerNorm: f32 in -> bf16 out (+ optional f32 out) ----------------
__global__ __launch_bounds__(256) void ln_kernel(const float* __restrict__ in,
                                                 const float* __restrict__ w,
                                                 const float* __restrict__ b,
                                                 u16* __restrict__ ob,
                                                 float* __restrict__ of){
    int row = blockIdx.x;
    int tid = threadIdx.x;
    const float* r = in + (size_t)row*Hz;
    float v0 = r[tid], v1 = r[tid+256];
    float s = v0+v1, q = v0*v0+v1*v1;
    #pragma unroll
    for (int o=32;o;o>>=1){ s += __shfl_down(s,o); q += __shfl_down(q,o); }
    __shared__ float ss[4], sq[4];
    __shared__ float mu_s, rs_s;
    int wid = tid>>6, lane = tid&63;
    if (lane==0){ ss[wid]=s; sq[wid]=q; }
    __syncthreads();
    if (tid==0){
        float S=ss[0]+ss[1]+ss[2]+ss[3];
        float Q=sq[0]+sq[1]+sq[2]+sq[3];
        float mu = S/(float)Hz;
        float var = Q/(float)Hz - mu*mu;
        mu_s = mu; rs_s = rsqrtf(var + EPSf);
    }
    __syncthreads();
    float mu = mu_s, rs = rs_s;
    float r0 = (v0-mu)*rs*w[tid]    +b[tid];
    float r1 = (v1-mu)*rs*w[tid+256]+b[tid+256];
    u16* o = ob + (size_t)row*Hz;
    o[tid] = f2b(r0); o[tid+256] = f2b(r1);
    if (of){
        float* p = of + (size_t)row*Hz;
        p[tid] = r0; p[tid+256] = r1;
    }
}

// ---------------- MFMA GEMM: C[N,M] = A[N,K] @ Bw[M,K]^T, bf16 in, f32 acc ----------------
// EPI 0: bf16 raw out   (outB)
// EPI 1: Y epilogue: h = gelu(2*acc + D[m]*fx) + fx ; hf read+write f32 (in-place over fx)
// EPI 2: OUT epilogue: outF = acc + b2f(resB)
#define EB16 0
#define EY   1
#define ERES 2

// stage 128x32 bf16 tile (8192B) from row-major src (leading dim K) into linear LDS
__device__ __forceinline__ void stage_tile(const u16* __restrict__ src, int ld,
                                           int row0, int kt, u16* lds){
    int lane = threadIdx.x & 63;
    int w    = threadIdx.x >> 6;
    #pragma unroll
    for (int q = 0; q < 2; ++q){
        int c = w + q*4;                  // 1024B chunk id, 0..7
        int r = c*16 + (lane >> 2);       // row in tile
        int colE = (lane & 3) * 8;        // element col in [0,32)
        const u16* g = src + (size_t)(row0 + r)*ld + kt + colE;
        gload_lds16(g, lds + c*512);      // wave-uniform LDS base; HW adds lane*16B
    }
}

template<int EPI>
__global__ __launch_bounds__(256)
void gemm_mfma(const u16* __restrict__ A, const u16* __restrict__ Bw,
               int K, int M,
               u16* __restrict__ outB,
               float* hf,                          // EY: read fx / write h (aliased)
               const float* __restrict__ Dv,       // EY
               const u16* __restrict__ resB,       // ERES
               float* __restrict__ outF)           // ERES
{
    __shared__ u16 Als[128*32];
    __shared__ u16 Bls[128*32];
    int n0 = blockIdx.x * 128;
    int m0 = blockIdx.y * 128;
    int lane = threadIdx.x & 63;
    int w = threadIdx.x >> 6;
    int wrow = (w >> 1) * 64, wcol = (w & 1) * 64;
    int fr  = lane & 15;
    int fk8 = (lane >> 4) * 8;

    f32x4 acc[4][4];
    #pragma unroll
    for (int i=0;i<4;++i)
        #pragma unroll
        for (int j=0;j<4;++j) acc[i][j] = (f32x4)(0.f);

    for (int kt = 0; kt < K; kt += 32){
        stage_tile(A,  K, n0, kt, Als);
        stage_tile(Bw, K, m0, kt, Bls);
        __syncthreads();
        bf16x8 af[4], bf[4];
        #pragma unroll
        for (int i=0;i<4;++i) af[i] = *(const bf16x8*)&Als[(wrow + i*16 + fr)*32 + fk8];
        #pragma unroll
        for (int j=0;j<4;++j) bf[j] = *(const bf16x8*)&Bls[(wcol + j*16 + fr)*32 + fk8];
        #pragma unroll
        for (int i=0;i<4;++i)
            #pragma unroll
            for (int j=0;j<4;++j)
                acc[i][j] = __builtin_amdgcn_mfma_f32_16x16x32_bf16(af[i], bf[j], acc[i][j], 0,0,0);
        __syncthreads();
    }

    int er = (lane >> 4) * 4;
    int ec = lane & 15;
    #pragma unroll
    for (int i=0;i<4;++i)
        #pragma unroll
        for (int j=0;j<4;++j)
            #pragma unroll
            for (int q=0;q<4;++q){
                int n = n0 + wrow + i*16 + er + q;
                int m = m0 + wcol + j*16 + ec;
                float v = acc[i][j][q];
                if (EPI == EB16){
                    outB[(size_t)n*M + m] = f2b(v);
                } else if (EPI == EY){
                    size_t idx = (size_t)n*Hz + m;
                    float fxv = hf[idx];
                    float y = 2.0f*v + Dv[m]*fxv;
                    hf[idx] = gelu_exact(y) + fxv;
                } else {
                    size_t idx = (size_t)n*Hz + m;
                    outF[idx] = v + b2f(resB[idx]);
                }
            }
}

// ---------------- scan (f folded in, bf16 I/O, f32 state) ----------------
// g layout: [N][1024], cols [0,512)=Re raw, [512,1024)=Im raw
__global__ __launch_bounds__(256) void scan_phase1(const u16* __restrict__ g,
                                                   const float* __restrict__ prm,
                                                   float* __restrict__ ERe,
                                                   float* __restrict__ EIm){
    int t = blockIdx.x;
    int pb = t & 1; t >>= 1;
    int c  = t % NC; t /= NC;
    int b  = t;
    int p  = pb*256 + threadIdx.x;
    size_t base = ((size_t)(b*Lz + c*CL))*1024 + p;
    float Ar = prm[p], Ai = prm[Pz+p];
    float fre = prm[2*Pz+p], fim = prm[3*Pz+p];
    float xr = 0.f, xi = 0.f;
    for (int l = 0; l < CL; ++l) {
        float gr = b2f(g[base]), gi = b2f(g[base+512]);
        float br = fre*gr - fim*gi;
        float bi = fre*gi + fim*gr;
        float nr = Ar*xr - Ai*xi + br;
        float ni = Ar*xi + Ai*xr + bi;
        xr = nr; xi = ni;
        base += 1024;
    }
    size_t ci = ((size_t)(b*NC + c))*Pz + p;
    ERe[ci] = xr; EIm[ci] = xi;
}

__global__ __launch_bounds__(256) void scan_combine(const float* __restrict__ ERe,
                                                    const float* __restrict__ EIm,
                                                    const float* __restrict__ prm,
                                                    float* __restrict__ SinRe,
                                                    float* __restrict__ SinIm){
    int gt = blockIdx.x*256 + threadIdx.x;   // over B*P
    int b = gt / Pz, p = gt % Pz;
    float Ar = prm[4*Pz+p], Ai = prm[5*Pz+p];
    float Sr = 0.f, Si = 0.f;
    for (int c = 0; c < NC; ++c) {
        size_t idx = ((size_t)(b*NC + c))*Pz + p;
        SinRe[idx] = Sr; SinIm[idx] = Si;
        float er = ERe[idx], ei = EIm[idx];
        float nr = Ar*Sr - Ai*Si + er;
        float ni = Ar*Si + Ai*Sr + ei;
        Sr = nr; Si = ni;
    }
}

// overwrites g with xs (bf16, same [re|im] layout)
__global__ __launch_bounds__(256) void scan_phase2(u16* __restrict__ g,
                                                   const float* __restrict__ prm,
                                                   const float* __restrict__ SinRe,
                                                   const float* __restrict__ SinIm){
    int t = blockIdx.x;
    int pb = t & 1; t >>= 1;
    int c  = t % NC; t /= NC;
    int b  = t;
    int p  = pb*256 + threadIdx.x;
    size_t base = ((size_t)(b*Lz + c*CL))*1024 + p;
    size_t ci = ((size_t)(b*NC + c))*Pz + p;
    float Ar = prm[p], Ai = prm[Pz+p];
    float fre = prm[2*Pz+p], fim = prm[3*Pz+p];
    float xr = SinRe[ci], xi = SinIm[ci];
    for (int l = 0; l < CL; ++l) {
        float gr = b2f(g[base]), gi = b2f(g[base+512]);
        float br = fre*gr - fim*gi;
        float bi = fre*gi + fim*gr;
        float nr = Ar*xr - Ai*xi + br;
        float ni = Ar*xi + Ai*xr + bi;
        xr = nr; xi = ni;
        g[base] = f2b(xr); g[base+512] = f2b(xi);
        base += 1024;
    }
}

// ---------------- GEGLU elementwise: ff = a * gelu(g) ----------------
__global__ __launch_bounds__(256) void geglu_kernel(const u16* __restrict__ e,
                                                    u16* __restrict__ ff){
    size_t i = (size_t)blockIdx.x*256 + threadIdx.x;  // over N*512
    int n = (int)(i >> 9), m = (int)(i & 511);
    float a = b2f(e[(size_t)n*1024 + m]);
    float gg = b2f(e[(size_t)n*1024 + 512 + m]);
    ff[i] = f2b(a * gelu_exact(gg));
}

extern "C" void kernel_launch(void* const* d_in, const int* in_sizes, int n_in,
                              void* d_out, int out_size, void* d_ws, size_t ws_size,
                              hipStream_t stream) {
    const float* x        = (const float*)d_in[0];
    const float* ln1_w    = (const float*)d_in[1];
    const float* ln1_b    = (const float*)d_in[2];
    const float* Lre      = (const float*)d_in[3];
    const float* Lim      = (const float*)d_in[4];
    const float* B_re     = (const float*)d_in[5];
    const float* B_im     = (const float*)d_in[6];
    const float* C_re     = (const float*)d_in[7];
    const float* C_im     = (const float*)d_in[8];
    const float* Dv       = (const float*)d_in[9];
    const float* log_step = (const float*)d_in[10];
    const float* ln2_w    = (const float*)d_in[11];
    const float* ln2_b    = (const float*)d_in[12];
    const float* W_enc    = (const float*)d_in[13];
    const float* W_dec    = (const float*)d_in[14];
    float* out = (float*)d_out;

    const size_t NH = (size_t)Nz*Hz;   // 8388608
    char* W = (char*)d_ws;
    float* fxf  = (float*)(W);                    // [N,512] f32 : fx, then h (in place)
    u16*   fxb  = (u16*)  (W + NH*4);             // [N,512] bf16: fx, then ff
    u16*   g    = (u16*)  (W + NH*6);             // [N,1024] bf16: g -> xs -> e
    u16*   fx2b = (u16*)  (W + NH*10);            // [N,512] bf16: fx2
    float* ERe  = (float*)(W + NH*12);
    float* EIm  = ERe + CS;
    float* SinRe= EIm + CS;
    float* SinIm= SinRe + CS;
    float* prm  = SinIm + CS;                     // 6*Pz f32
    u16*   Bcat = (u16*)(prm + 6*Pz);             // [1024,512]
    u16*   Ccat = Bcat + 1024*512;                // [512,1024]
    u16*   Wenc = Ccat + 512*1024;                // [1024,512]
    u16*   Wdec = Wenc + 1024*512;                // [512,512]

    setup_kernel<<<dim3(2), dim3(256), 0, stream>>>(Lre, Lim, log_step, prm);

    cvt_f2b_kernel<<<dim3(1024), dim3(256), 0, stream>>>(B_re, Bcat,          512*512);
    cvt_f2b_kernel<<<dim3(1024), dim3(256), 0, stream>>>(B_im, Bcat+512*512,  512*512);
    cvt_ccat_kernel<<<dim3(1024), dim3(256), 0, stream>>>(C_re, C_im, Ccat);
    cvt_f2b_kernel<<<dim3(2048), dim3(256), 0, stream>>>(W_enc, Wenc, 1024*512);
    cvt_f2b_kernel<<<dim3(1024), dim3(256), 0, stream>>>(W_dec, Wdec, 512*512);

    // LN1: x -> fxb (bf16) + fxf (f32)
    ln_kernel<<<dim3(Nz), dim3(256), 0, stream>>>(x, ln1_w, ln1_b, fxb, fxf);

    // GEMM1: g = fxb @ Bcat^T   [N,1024]
    gemm_mfma<EB16><<<dim3(Nz/128, 1024/128), dim3(256), 0, stream>>>(
        fxb, Bcat, 512, 1024, g, nullptr, nullptr, nullptr, nullptr);

    // scan: g (raw) -> xs (in place), f-scaling applied on load
    scan_phase1<<<dim3(Bz*NC*2), dim3(256), 0, stream>>>(g, prm, ERe, EIm);
    scan_combine<<<dim3((Bz*Pz)/256), dim3(256), 0, stream>>>(ERe, EIm, prm, SinRe, SinIm);
    scan_phase2<<<dim3(Bz*NC*2), dim3(256), 0, stream>>>(g, prm, SinRe, SinIm);

    // GEMM2 (Y): h = gelu(2*(xs@Ccat^T) + D*fx) + fx, in-place over fxf
    gemm_mfma<EY><<<dim3(Nz/128, 512/128), dim3(256), 0, stream>>>(
        g, Ccat, 1024, 512, nullptr, fxf, Dv, nullptr, nullptr);

    // LN2: h -> fx2b (bf16 only)
    ln_kernel<<<dim3(Nz), dim3(256), 0, stream>>>(fxf, ln2_w, ln2_b, fx2b, nullptr);

    // GEMM3: e = fx2b @ Wenc^T  [N,1024]  (over g slot)
    gemm_mfma<EB16><<<dim3(Nz/128, 1024/128), dim3(256), 0, stream>>>(
        fx2b, Wenc, 512, 1024, g, nullptr, nullptr, nullptr, nullptr);

    // GEGLU: ff = a * gelu(gg)  (over fxb slot)
    geglu_kernel<<<dim3((unsigned)(NH/256)), dim3(256), 0, stream>>>(g, fxb);

    // GEMM4: out = ff @ Wdec^T + fx2
    gemm_mfma<ERES><<<dim3(Nz/128, 512/128), dim3(256), 0, stream>>>(
        fxb, Wdec, 512, 512, nullptr, nullptr, nullptr, fx2b, out);
}

// Round 3
// 216.759 us; speedup vs baseline: 6.2858x; 1.0474x over previous
//
#include <hip/hip_runtime.h>
#include <math.h>

// (B,L,H,P) = (4,4096,512,512)
#define Bz 4
#define Lz 4096
#define Hz 512
#define Pz 512
#define Nz (Bz*Lz)          // 16384 rows
#define CL 64               // scan chunk length
#define NC (Lz/CL)          // 64 chunks
#define CS (Bz*NC*Pz)       // 131072 carry slots
#define EPSf 1e-5f

typedef unsigned short u16;
typedef unsigned int   u32;
typedef __attribute__((ext_vector_type(8))) short bf16x8;
typedef __attribute__((ext_vector_type(4))) float f32x4;

__device__ __forceinline__ float gelu_exact(float x){
    return 0.5f * x * (1.0f + erff(x * 0.70710678118654752f));
}
__device__ __forceinline__ u16 f2b(float f){
    union { float f; u32 u; } v; v.f = f;
    u32 u = v.u;
    u32 r = (u + 0x7FFFu + ((u >> 16) & 1u)) >> 16;   // RTNE
    return (u16)r;
}
__device__ __forceinline__ float b2f(u16 h){
    union { u32 u; float f; } v; v.u = ((u32)h) << 16; return v.f;
}

__device__ __forceinline__ void gload_lds16(const u16* g, u16* l){
    __builtin_amdgcn_global_load_lds(
        (const __attribute__((address_space(1))) void*)g,
        (__attribute__((address_space(3))) void*)l, 16, 0, 0);
}

// ---------------- setup: per-state SSM params ----------------
__global__ void setup_kernel(const float* __restrict__ Lre, const float* __restrict__ Lim,
                             const float* __restrict__ log_step,
                             float* __restrict__ prm){
    int p = blockIdx.x*blockDim.x + threadIdx.x;
    if (p >= Pz) return;
    float lr = Lre[p], li = Lim[p];
    float dt = expf(log_step[p]);
    float ar = lr*dt, ai = li*dt;
    float e = expf(ar);
    float Abr = e*cosf(ai), Abi = e*sinf(ai);   // Lambda_bar
    prm[p]        = Abr;   // LamBarRe
    prm[Pz + p]   = Abi;   // LamBarIm
    float nr = Abr - 1.0f, ni = Abi;
    float d2 = lr*lr + li*li;
    prm[2*Pz + p] = (nr*lr + ni*li)/d2;   // fRe
    prm[3*Pz + p] = (ni*lr - nr*li)/d2;   // fIm
    float arC = ar*(float)CL, aiC = ai*(float)CL;
    float eC = expf(arC);
    prm[4*Pz + p] = eC*cosf(aiC);         // ApowRe
    prm[5*Pz + p] = eC*sinf(aiC);         // ApowIm
}

// ---------------- merged weight converts (one launch) ----------------
__global__ __launch_bounds__(256) void cvt_all(const float* __restrict__ B_re,
                                               const float* __restrict__ B_im,
                                               const float* __restrict__ C_re,
                                               const float* __restrict__ C_im,
                                               const float* __restrict__ W_enc,
                                               const float* __restrict__ W_dec,
                                               u16* __restrict__ Bcat,
                                               u16* __restrict__ Ccat,
                                               u16* __restrict__ Wenc,
                                               u16* __restrict__ Wdec){
    const int Q = 512*512;
    int i = blockIdx.x*256 + threadIdx.x;
    if (i < Q){ Bcat[i] = f2b(B_re[i]); return; }
    i -= Q;
    if (i < Q){ Bcat[Q + i] = f2b(B_im[i]); return; }
    i -= Q;
    if (i < Q){
        int h = i >> 9, p = i & 511;
        Ccat[(size_t)h*1024 + p]       = f2b(C_re[i]);
        Ccat[(size_t)h*1024 + 512 + p] = f2b(-C_im[i]);
        return;
    }
    i -= Q;
    if (i < 2*Q){ Wenc[i] = f2b(W_enc[i]); return; }
    i -= 2*Q;
    Wdec[i] = f2b(W_dec[i]);
}

// ---------------- LayerNorm: f32 in -> bf16 out (+ optional f32 out) ----------------
__global__ __launch_bounds__(256) void ln_kernel(const float* __restrict__ in,
                                                 const float* __restrict__ w,
                                                 const float* __restrict__ b,
                                                 u16* __restrict__ ob,
                                                 float* __restrict__ of){
    int row = blockIdx.x;
    int tid = threadIdx.x;
    const float* r = in + (size_t)row*Hz;
    float v0 = r[tid], v1 = r[tid+256];
    float s = v0+v1, q = v0*v0+v1*v1;
    #pragma unroll
    for (int o=32;o;o>>=1){ s += __shfl_down(s,o); q += __shfl_down(q,o); }
    __shared__ float ss[4], sq[4];
    __shared__ float mu_s, rs_s;
    int wid = tid>>6, lane = tid&63;
    if (lane==0){ ss[wid]=s; sq[wid]=q; }
    __syncthreads();
    if (tid==0){
        float S=ss[0]+ss[1]+ss[2]+ss[3];
        float Q=sq[0]+sq[1]+sq[2]+sq[3];
        float mu = S/(float)Hz;
        float var = Q/(float)Hz - mu*mu;
        mu_s = mu; rs_s = rsqrtf(var + EPSf);
    }
    __syncthreads();
    float mu = mu_s, rs = rs_s;
    float r0 = (v0-mu)*rs*w[tid]    +b[tid];
    float r1 = (v1-mu)*rs*w[tid+256]+b[tid+256];
    u16* o = ob + (size_t)row*Hz;
    o[tid] = f2b(r0); o[tid+256] = f2b(r1);
    if (of){
        float* p = of + (size_t)row*Hz;
        p[tid] = r0; p[tid+256] = r1;
    }
}

// ---------------- MFMA GEMM: C[N,M] = A[N,K] @ Bw[M,K]^T, bf16 in, f32 acc ----------------
#define EB16 0
#define EY   1
#define ERES 2

// stage 128x32 bf16 tile (8192B) from row-major src (ld=K) into linear LDS [128][32]
__device__ __forceinline__ void stage_tile(const u16* __restrict__ src, int ld,
                                           int row0, int kt, u16* lds){
    int lane = threadIdx.x & 63;
    int w    = threadIdx.x >> 6;
    #pragma unroll
    for (int q = 0; q < 2; ++q){
        int c = w + q*4;                  // 1024B chunk id, 0..7
        int r = c*16 + (lane >> 2);       // row in tile
        int colE = (lane & 3) * 8;        // element col in [0,32)
        const u16* g = src + (size_t)(row0 + r)*ld + kt + colE;
        gload_lds16(g, lds + c*512);      // wave-uniform LDS base; HW adds lane*16B
    }
}

template<int EPI>
__global__ __launch_bounds__(256)
void gemm_mfma(const u16* __restrict__ A, const u16* __restrict__ Bw,
               int K, int M,
               u16* __restrict__ outB,
               float* hf,                          // EY: read fx / write h (aliased)
               const float* __restrict__ Dv,       // EY
               const u16* __restrict__ resB,       // ERES
               float* __restrict__ outF)           // ERES
{
    __shared__ u16 Als[2][128*32];
    __shared__ u16 Bls[2][128*32];

    // XCD-aware bijective swizzle: each XCD owns a contiguous bx-range, by fastest.
    int nx = gridDim.x, ny = gridDim.y;
    int nwg = nx*ny;                       // always %8==0 here
    int lid = blockIdx.x + blockIdx.y*nx;  // HW dispatch order (x fastest)
    int cpx = nwg >> 3;
    int gdx = (lid & 7)*cpx + (lid >> 3);
    int n0 = (gdx / ny) * 128;
    int m0 = (gdx % ny) * 128;

    int lane = threadIdx.x & 63;
    int w = threadIdx.x >> 6;
    int wrow = (w >> 1) * 64, wcol = (w & 1) * 64;
    int fr  = lane & 15;
    int fk8 = (lane >> 4) * 8;

    f32x4 acc[4][4];
    #pragma unroll
    for (int i=0;i<4;++i)
        #pragma unroll
        for (int j=0;j<4;++j) acc[i][j] = (f32x4)(0.f);

    // prologue: stage tile 0 into buffer 0
    stage_tile(A,  K, n0, 0, &Als[0][0]);
    stage_tile(Bw, K, m0, 0, &Bls[0][0]);
    __syncthreads();

    int cur = 0;
    for (int kt = 32; kt < K; kt += 32){
        // issue next-tile loads first (overlap with this tile's compute)
        stage_tile(A,  K, n0, kt, &Als[cur^1][0]);
        stage_tile(Bw, K, m0, kt, &Bls[cur^1][0]);
        bf16x8 af[4], bf4[4];
        #pragma unroll
        for (int i=0;i<4;++i) af[i]  = *(const bf16x8*)&Als[cur][(wrow + i*16 + fr)*32 + fk8];
        #pragma unroll
        for (int j=0;j<4;++j) bf4[j] = *(const bf16x8*)&Bls[cur][(wcol + j*16 + fr)*32 + fk8];
        #pragma unroll
        for (int i=0;i<4;++i)
            #pragma unroll
            for (int j=0;j<4;++j)
                acc[i][j] = __builtin_amdgcn_mfma_f32_16x16x32_bf16(af[i], bf4[j], acc[i][j], 0,0,0);
        __syncthreads();   // drains vmcnt (next tile ready) + lgkm; frees buf[cur]
        cur ^= 1;
    }
    {   // epilogue tile (no prefetch)
        bf16x8 af[4], bf4[4];
        #pragma unroll
        for (int i=0;i<4;++i) af[i]  = *(const bf16x8*)&Als[cur][(wrow + i*16 + fr)*32 + fk8];
        #pragma unroll
        for (int j=0;j<4;++j) bf4[j] = *(const bf16x8*)&Bls[cur][(wcol + j*16 + fr)*32 + fk8];
        #pragma unroll
        for (int i=0;i<4;++i)
            #pragma unroll
            for (int j=0;j<4;++j)
                acc[i][j] = __builtin_amdgcn_mfma_f32_16x16x32_bf16(af[i], bf4[j], acc[i][j], 0,0,0);
    }

    int er = (lane >> 4) * 4;
    int ec = lane & 15;
    #pragma unroll
    for (int i=0;i<4;++i)
        #pragma unroll
        for (int j=0;j<4;++j)
            #pragma unroll
            for (int q=0;q<4;++q){
                int n = n0 + wrow + i*16 + er + q;
                int m = m0 + wcol + j*16 + ec;
                float v = acc[i][j][q];
                if (EPI == EB16){
                    outB[(size_t)n*M + m] = f2b(v);
                } else if (EPI == EY){
                    size_t idx = (size_t)n*Hz + m;
                    float fxv = hf[idx];
                    float y = 2.0f*v + Dv[m]*fxv;
                    hf[idx] = gelu_exact(y) + fxv;
                } else {
                    size_t idx = (size_t)n*Hz + m;
                    outF[idx] = v + b2f(resB[idx]);
                }
            }
}

// ---------------- scan (f folded in, bf16 I/O, f32 state) ----------------
// g layout: [N][1024], cols [0,512)=Re raw, [512,1024)=Im raw
__global__ __launch_bounds__(256) void scan_phase1(const u16* __restrict__ g,
                                                   const float* __restrict__ prm,
                                                   float* __restrict__ ERe,
                                                   float* __restrict__ EIm){
    int t = blockIdx.x;
    int pb = t & 1; t >>= 1;
    int c  = t % NC; t /= NC;
    int b  = t;
    int p  = pb*256 + threadIdx.x;
    size_t base = ((size_t)(b*Lz + c*CL))*1024 + p;
    float Ar = prm[p], Ai = prm[Pz+p];
    float fre = prm[2*Pz+p], fim = prm[3*Pz+p];
    float xr = 0.f, xi = 0.f;
    for (int l = 0; l < CL; ++l) {
        float gr = b2f(g[base]), gi = b2f(g[base+512]);
        float br = fre*gr - fim*gi;
        float bi = fre*gi + fim*gr;
        float nr = Ar*xr - Ai*xi + br;
        float ni = Ar*xi + Ai*xr + bi;
        xr = nr; xi = ni;
        base += 1024;
    }
    size_t ci = ((size_t)(b*NC + c))*Pz + p;
    ERe[ci] = xr; EIm[ci] = xi;
}

__global__ __launch_bounds__(256) void scan_combine(const float* __restrict__ ERe,
                                                    const float* __restrict__ EIm,
                                                    const float* __restrict__ prm,
                                                    float* __restrict__ SinRe,
                                                    float* __restrict__ SinIm){
    int gt = blockIdx.x*256 + threadIdx.x;   // over B*P
    int b = gt / Pz, p = gt % Pz;
    float Ar = prm[4*Pz+p], Ai = prm[5*Pz+p];
    float Sr = 0.f, Si = 0.f;
    for (int c = 0; c < NC; ++c) {
        size_t idx = ((size_t)(b*NC + c))*Pz + p;
        SinRe[idx] = Sr; SinIm[idx] = Si;
        float er = ERe[idx], ei = EIm[idx];
        float nr = Ar*Sr - Ai*Si + er;
        float ni = Ar*Si + Ai*Sr + ei;
        Sr = nr; Si = ni;
    }
}

// overwrites g with xs (bf16, same [re|im] layout)
__global__ __launch_bounds__(256) void scan_phase2(u16* __restrict__ g,
                                                   const float* __restrict__ prm,
                                                   const float* __restrict__ SinRe,
                                                   const float* __restrict__ SinIm){
    int t = blockIdx.x;
    int pb = t & 1; t >>= 1;
    int c  = t % NC; t /= NC;
    int b  = t;
    int p  = pb*256 + threadIdx.x;
    size_t base = ((size_t)(b*Lz + c*CL))*1024 + p;
    size_t ci = ((size_t)(b*NC + c))*Pz + p;
    float Ar = prm[p], Ai = prm[Pz+p];
    float fre = prm[2*Pz+p], fim = prm[3*Pz+p];
    float xr = SinRe[ci], xi = SinIm[ci];
    for (int l = 0; l < CL; ++l) {
        float gr = b2f(g[base]), gi = b2f(g[base+512]);
        float br = fre*gr - fim*gi;
        float bi = fre*gi + fim*gr;
        float nr = Ar*xr - Ai*xi + br;
        float ni = Ar*xi + Ai*xr + bi;
        xr = nr; xi = ni;
        g[base] = f2b(xr); g[base+512] = f2b(xi);
        base += 1024;
    }
}

// ---------------- GEGLU elementwise: ff = a * gelu(g) ----------------
__global__ __launch_bounds__(256) void geglu_kernel(const u16* __restrict__ e,
                                                    u16* __restrict__ ff){
    size_t i = (size_t)blockIdx.x*256 + threadIdx.x;  // over N*512
    int n = (int)(i >> 9), m = (int)(i & 511);
    float a = b2f(e[(size_t)n*1024 + m]);
    float gg = b2f(e[(size_t)n*1024 + 512 + m]);
    ff[i] = f2b(a * gelu_exact(gg));
}

extern "C" void kernel_launch(void* const* d_in, const int* in_sizes, int n_in,
                              void* d_out, int out_size, void* d_ws, size_t ws_size,
                              hipStream_t stream) {
    const float* x        = (const float*)d_in[0];
    const float* ln1_w    = (const float*)d_in[1];
    const float* ln1_b    = (const float*)d_in[2];
    const float* Lre      = (const float*)d_in[3];
    const float* Lim      = (const float*)d_in[4];
    const float* B_re     = (const float*)d_in[5];
    const float* B_im     = (const float*)d_in[6];
    const float* C_re     = (const float*)d_in[7];
    const float* C_im     = (const float*)d_in[8];
    const float* Dv       = (const float*)d_in[9];
    const float* log_step = (const float*)d_in[10];
    const float* ln2_w    = (const float*)d_in[11];
    const float* ln2_b    = (const float*)d_in[12];
    const float* W_enc    = (const float*)d_in[13];
    const float* W_dec    = (const float*)d_in[14];
    float* out = (float*)d_out;

    const size_t NH = (size_t)Nz*Hz;   // 8388608
    char* W = (char*)d_ws;
    float* fxf  = (float*)(W);                    // [N,512] f32 : fx, then h (in place)
    u16*   fxb  = (u16*)  (W + NH*4);             // [N,512] bf16: fx, then ff
    u16*   g    = (u16*)  (W + NH*6);             // [N,1024] bf16: g -> xs -> e
    u16*   fx2b = (u16*)  (W + NH*10);            // [N,512] bf16: fx2
    float* ERe  = (float*)(W + NH*12);
    float* EIm  = ERe + CS;
    float* SinRe= EIm + CS;
    float* SinIm= SinRe + CS;
    float* prm  = SinIm + CS;                     // 6*Pz f32
    u16*   Bcat = (u16*)(prm + 6*Pz);             // [1024,512]
    u16*   Ccat = Bcat + 1024*512;                // [512,1024]
    u16*   Wenc = Ccat + 512*1024;                // [1024,512]
    u16*   Wdec = Wenc + 1024*512;                // [512,512]

    setup_kernel<<<dim3(2), dim3(256), 0, stream>>>(Lre, Lim, log_step, prm);

    cvt_all<<<dim3(6*1024), dim3(256), 0, stream>>>(B_re, B_im, C_re, C_im, W_enc, W_dec,
                                                    Bcat, Ccat, Wenc, Wdec);

    // LN1: x -> fxb (bf16) + fxf (f32)
    ln_kernel<<<dim3(Nz), dim3(256), 0, stream>>>(x, ln1_w, ln1_b, fxb, fxf);

    // GEMM1: g = fxb @ Bcat^T   [N,1024]
    gemm_mfma<EB16><<<dim3(Nz/128, 1024/128), dim3(256), 0, stream>>>(
        fxb, Bcat, 512, 1024, g, nullptr, nullptr, nullptr, nullptr);

    // scan: g (raw) -> xs (in place), f-scaling applied on load
    scan_phase1<<<dim3(Bz*NC*2), dim3(256), 0, stream>>>(g, prm, ERe, EIm);
    scan_combine<<<dim3((Bz*Pz)/256), dim3(256), 0, stream>>>(ERe, EIm, prm, SinRe, SinIm);
    scan_phase2<<<dim3(Bz*NC*2), dim3(256), 0, stream>>>(g, prm, SinRe, SinIm);

    // GEMM2 (Y): h = gelu(2*(xs@Ccat^T) + D*fx) + fx, in-place over fxf
    gemm_mfma<EY><<<dim3(Nz/128, 512/128), dim3(256), 0, stream>>>(
        g, Ccat, 1024, 512, nullptr, fxf, Dv, nullptr, nullptr);

    // LN2: h -> fx2b (bf16 only)
    ln_kernel<<<dim3(Nz), dim3(256), 0, stream>>>(fxf, ln2_w, ln2_b, fx2b, nullptr);

    // GEMM3: e = fx2b @ Wenc^T  [N,1024]  (over g slot)
    gemm_mfma<EB16><<<dim3(Nz/128, 1024/128), dim3(256), 0, stream>>>(
        fx2b, Wenc, 512, 1024, g, nullptr, nullptr, nullptr, nullptr);

    // GEGLU: ff = a * gelu(gg)  (over fxb slot)
    geglu_kernel<<<dim3((unsigned)(NH/256)), dim3(256), 0, stream>>>(g, fxb);

    // GEMM4: out = ff @ Wdec^T + fx2
    gemm_mfma<ERES><<<dim3(Nz/128, 512/128), dim3(256), 0, stream>>>(
        fxb, Wdec, 512, 512, nullptr, nullptr, nullptr, fx2b, out);
}